// Round 9
// baseline (310.695 us; speedup 1.0000x reference)
//
#include <hip/hip_runtime.h>
#include <math.h>

// Problem constants (fixed by reference):
// B=2, L=2048, D=2048, H=16, G=4, HD=128, EPS=1e-6, scale = 1/HD^2 = 1/16384
#define SEQ 2048
#define DMODEL 2048
#define NHQ 16
#define NHK 4

typedef __attribute__((ext_vector_type(8))) short short8;
typedef __attribute__((ext_vector_type(8))) unsigned short ushort8;
typedef __attribute__((ext_vector_type(4))) float floatx4;

#define AS1 __attribute__((address_space(1)))
#define AS3 __attribute__((address_space(3)))

__device__ __forceinline__ unsigned short f2bf(float f) {
  unsigned int u = __builtin_bit_cast(unsigned int, f);
  u += 0x7fffu + ((u >> 16) & 1u);   // round-to-nearest-even
  return (unsigned short)(u >> 16);
}
__device__ __forceinline__ float bf2f(unsigned short s) {
  unsigned int u = ((unsigned int)s) << 16;
  return __builtin_bit_cast(float, u);
}

// ---------------------------------------------------------------------------
// One prep launch: cast x -> bf16 AND all 4 weight transposes. (unchanged)
// ---------------------------------------------------------------------------
__global__ __launch_bounds__(256) void prep(const float* __restrict__ x,
                                            const float* __restrict__ Wq,
                                            const float* __restrict__ Wk,
                                            const float* __restrict__ Wv,
                                            const float* __restrict__ Wo,
                                            unsigned short* __restrict__ x_bf,
                                            unsigned short* __restrict__ wqkv_t,
                                            unsigned short* __restrict__ wo_t) {
  const int z = blockIdx.z;
  const int tx = threadIdx.x, ty = threadIdx.y;
  const int tid = ty * 32 + tx;
  if (z == 3) {
    const size_t base = ((size_t)(blockIdx.y * 64 + blockIdx.x)) * 4096 + (size_t)tid * 16;
    const float4 v0 = *(const float4*)(x + base);
    const float4 v1 = *(const float4*)(x + base + 4);
    const float4 v2 = *(const float4*)(x + base + 8);
    const float4 v3 = *(const float4*)(x + base + 12);
    ushort8 w0, w1;
    w0[0] = f2bf(v0.x); w0[1] = f2bf(v0.y); w0[2] = f2bf(v0.z); w0[3] = f2bf(v0.w);
    w0[4] = f2bf(v1.x); w0[5] = f2bf(v1.y); w0[6] = f2bf(v1.z); w0[7] = f2bf(v1.w);
    w1[0] = f2bf(v2.x); w1[1] = f2bf(v2.y); w1[2] = f2bf(v2.z); w1[3] = f2bf(v2.w);
    w1[4] = f2bf(v3.x); w1[5] = f2bf(v3.y); w1[6] = f2bf(v3.z); w1[7] = f2bf(v3.w);
    *(ushort8*)(x_bf + base) = w0;
    *(ushort8*)(x_bf + base + 8) = w1;
    return;
  }
  int bx = blockIdx.x;
  const float* in;
  unsigned short* out;
  int C;
  const int R = 2048;
  if (z == 0)      { in = Wq; out = wqkv_t;                          C = 2048; }
  else if (z == 1) { in = Wo; out = wo_t;                            C = 2048; }
  else {
    if (bx < 16)      { in = Wk; out = wqkv_t + (size_t)2048 * 2048; C = 512; }
    else if (bx < 32) { in = Wv; out = wqkv_t + (size_t)2560 * 2048; C = 512; bx -= 16; }
    else return;
  }
  __shared__ float tile[32][65];
  const int c0 = bx * 32, r0 = blockIdx.y * 64;
#pragma unroll
  for (int j = 0; j < 8; ++j)
    tile[tx][ty + j * 8] = in[(size_t)(r0 + ty + j * 8) * C + c0 + tx];
  __syncthreads();
  const int c = tid >> 3;
  const int l8 = tid & 7;
  ushort8 w;
#pragma unroll
  for (int u = 0; u < 8; ++u) w[u] = f2bf(tile[c][l8 * 8 + u]);
  *(ushort8*)(out + (size_t)(c0 + c) * R + r0 + l8 * 8) = w;
}

// ---------------------------------------------------------------------------
// Shared pipeline pieces (R15-verified swizzle + counted vmcnt).
// ---------------------------------------------------------------------------
#define PBAR() do { __builtin_amdgcn_sched_barrier(0); __builtin_amdgcn_s_barrier(); \
                    __builtin_amdgcn_sched_barrier(0); } while (0)
#define KWAIT8(deep) do { if (deep) asm volatile("s_waitcnt vmcnt(8)" ::: "memory"); \
                          else      asm volatile("s_waitcnt vmcnt(0)" ::: "memory"); } while (0)
#define KWAIT6(deep) do { if (deep) asm volatile("s_waitcnt vmcnt(6)" ::: "memory"); \
                          else      asm volatile("s_waitcnt vmcnt(0)" ::: "memory"); } while (0)

__device__ __forceinline__ void mfma_q(floatx4 (&ac)[4][4],
                                       const short8 (&a)[4], const short8 (&b)[4]) {
#pragma unroll
  for (int i = 0; i < 4; ++i)
#pragma unroll
    for (int j = 0; j < 4; ++j)
      ac[i][j] = __builtin_amdgcn_mfma_f32_16x16x32_bf16(a[i], b[j], ac[i][j], 0, 0, 0);
}

__device__ __forceinline__ void ld4(short8 (&v)[4], const unsigned short* p) {
#pragma unroll
  for (int i = 0; i < 4; ++i) v[i] = *(const short8*)(p + i * 512);
}
__device__ __forceinline__ void ld6(short8 (&v)[6], const unsigned short* p) {
#pragma unroll
  for (int i = 0; i < 6; ++i) v[i] = *(const short8*)(p + i * 512);
}

__device__ __forceinline__ void stg1(const unsigned short* src0,
                                     unsigned short* dst_uniform) {
  __builtin_amdgcn_global_load_lds((const AS1 void*)src0,
                                   (AS3 void*)dst_uniform, 16, 0, 0);
}
__device__ __forceinline__ void stg2(const unsigned short* src0,
                                     unsigned short* dst_uniform) {
  __builtin_amdgcn_global_load_lds((const AS1 void*)src0,
                                   (AS3 void*)dst_uniform, 16, 0, 0);
  __builtin_amdgcn_global_load_lds((const AS1 void*)(src0 + (size_t)128 * 2048),
                                   (AS3 void*)(dst_uniform + 4096), 16, 0, 0);
}
__device__ __forceinline__ void stg3(const unsigned short* src0,
                                     unsigned short* dst_uniform) {
  __builtin_amdgcn_global_load_lds((const AS1 void*)src0,
                                   (AS3 void*)dst_uniform, 16, 0, 0);
  __builtin_amdgcn_global_load_lds((const AS1 void*)(src0 + (size_t)128 * 2048),
                                   (AS3 void*)(dst_uniform + 4096), 16, 0, 0);
  __builtin_amdgcn_global_load_lds((const AS1 void*)(src0 + (size_t)256 * 2048),
                                   (AS3 void*)(dst_uniform + 8192), 16, 0, 0);
}

// ---------------------------------------------------------------------------
// Fused QKV GEMM + RMSNorm + RoPE + V-transpose, 128x384. (unchanged from R8)
// ---------------------------------------------------------------------------
__global__ __launch_bounds__(512, 2) void gemm_qkv_fused(const unsigned short* __restrict__ A,
                                                         const unsigned short* __restrict__ Bt,
                                                         unsigned short* __restrict__ qout,
                                                         unsigned short* __restrict__ kout,
                                                         unsigned short* __restrict__ vout,
                                                         const float* __restrict__ q_scale,
                                                         const float* __restrict__ k_scale,
                                                         const float* __restrict__ cosb,
                                                         const float* __restrict__ sinb) {
  __shared__ unsigned short lds[65536];   // 128 KB
  unsigned short* ldsA = lds;             // [buf*8192][kh*4096][128x32]
  unsigned short* ldsB = lds + 16384;     // [buf*24576][kh*12288][384x32]

  const int tid = threadIdx.x;
  const int wave = tid >> 6;
  const int lane = tid & 63;
  const int m15 = lane & 15;
  const int quad = lane >> 4;
  const int wr = wave >> 2;
  const int wcol = wave & 3;
  const int bxn = blockIdx.x;
  const int bm = blockIdx.y * 128;
  const int bn = bxn * 384;

  floatx4 acc[4][6];
#pragma unroll
  for (int i = 0; i < 4; ++i)
#pragma unroll
    for (int j = 0; j < 6; ++j) acc[i][j] = (floatx4){0.f, 0.f, 0.f, 0.f};

  const int srow = tid >> 2;
  const int csrc = ((tid & 3) ^ ((tid >> 3) & 3)) * 8;
  const unsigned short* gA = A + (size_t)(bm + srow) * 2048 + csrc;
  const unsigned short* gB = Bt + (size_t)(bn + srow) * 2048 + csrc;
  const int wslot = wave * 512;

  const int rc = (quad ^ ((m15 >> 1) & 3)) * 8;
  const int aoff = (wr * 64 + m15) * 32 + rc;
  const int boff = (wcol * 96 + m15) * 32 + rc;

  stg1(gA + 0,  ldsA + wslot);
  stg3(gB + 0,  ldsB + wslot);
  stg1(gA + 32, ldsA + 4096 + wslot);
  stg3(gB + 32, ldsB + 12288 + wslot);
  stg1(gA + 64, ldsA + 8192 + wslot);
  stg3(gB + 64, ldsB + 24576 + wslot);
  asm volatile("s_waitcnt vmcnt(0)" ::: "memory");
  __builtin_amdgcn_s_barrier();
  __builtin_amdgcn_sched_barrier(0);

  const int NK = 32;
  short8 af[4], bv[6];
  for (int t = 0; t < NK; ++t) {
    const int d = t & 1;
    unsigned short* Ab = ldsA + d * 8192;
    unsigned short* Bb = ldsB + d * 24576;
    unsigned short* Aalt = ldsA + (d ^ 1) * 8192;
    unsigned short* Balt = ldsB + (d ^ 1) * 24576;
    const bool st1 = (t + 1 < NK), st2 = (t + 2 < NK);
    const int k1 = (t + 1) * 64 + 32;
    const int k2 = (t + 2) * 64;

    ld4(af, Ab + aoff);
    ld6(bv, Bb + boff);
    if (st1) { stg1(gA + k1, Aalt + 4096 + wslot);
               stg3(gB + k1, Balt + 12288 + wslot); }
    PBAR();
    __builtin_amdgcn_s_setprio(1);
#pragma unroll
    for (int i = 0; i < 4; ++i)
#pragma unroll
      for (int j = 0; j < 6; ++j)
        acc[i][j] = __builtin_amdgcn_mfma_f32_16x16x32_bf16(af[i], bv[j], acc[i][j], 0, 0, 0);
    __builtin_amdgcn_s_setprio(0);
    KWAIT8(st2);
    PBAR();

    ld4(af, Ab + 4096 + aoff);
    ld6(bv, Bb + 12288 + boff);
    if (st2) { stg1(gA + k2, Ab + wslot);
               stg3(gB + k2, Bb + wslot); }
    PBAR();
    __builtin_amdgcn_s_setprio(1);
#pragma unroll
    for (int i = 0; i < 4; ++i)
#pragma unroll
      for (int j = 0; j < 6; ++j)
        acc[i][j] = __builtin_amdgcn_mfma_f32_16x16x32_bf16(af[i], bv[j], acc[i][j], 0, 0, 0);
    __builtin_amdgcn_s_setprio(0);
    KWAIT8(st2);
    PBAR();
  }

  // ---- epilogue: three per-head passes through a 128x129 LDS region.
  unsigned short* epi = lds;
  const int b = bm >> 11;
  const int l_base = bm & (SEQ - 1);
  const int t64 = tid & 63;

  for (int c = 0; c < 3; ++c) {
    __syncthreads();
#pragma unroll
    for (int j = 0; j < 6; ++j) {
      const int head16 = 6 * wcol + j;
      if ((head16 >> 3) == c) {
        const int incol = (head16 & 7) * 16 + m15;
#pragma unroll
        for (int i = 0; i < 4; ++i)
#pragma unroll
          for (int r = 0; r < 4; ++r)
            epi[(wr * 64 + i * 16 + quad * 4 + r) * 129 + incol] = f2bf(acc[i][j][r]);
      }
    }
    __syncthreads();

    const int hh = 3 * bxn + c;
    if (hh < 20) {
      const float* scale = (hh < NHQ) ? q_scale : k_scale;
      unsigned short* dstbase = (hh < NHQ)
          ? qout + ((size_t)(b * NHQ + hh) * SEQ + l_base) * 128
          : kout + ((size_t)(b * NHK + (hh - NHQ)) * SEQ + l_base) * 128;
      const float sc0 = scale[t64];
      const float sc1 = scale[t64 + 64];
#pragma unroll 4
      for (int rr = 0; rr < 16; ++rr) {
        const int row = wave * 16 + rr;
        const float v0 = bf2f(epi[row * 129 + t64]);
        const float v1 = bf2f(epi[row * 129 + t64 + 64]);
        float ss = v0 * v0 + v1 * v1;
#pragma unroll
        for (int m = 1; m < 64; m <<= 1) ss += __shfl_xor(ss, m);
        const float r = rsqrtf(ss * (1.0f / 128.0f) + 1e-6f);
        const int l = l_base + row;
        const float c0v = cosb[(size_t)l * 128 + t64];
        const float s0 = sinb[(size_t)l * 128 + t64];
        const float c1v = cosb[(size_t)l * 128 + t64 + 64];
        const float s1 = sinb[(size_t)l * 128 + t64 + 64];
        const float a0 = v0 * r * sc0;
        const float a1 = v1 * r * sc1;
        unsigned short* dst = dstbase + (size_t)row * 128;
        dst[t64]      = f2bf(a0 * c0v - a1 * s0);
        dst[t64 + 64] = f2bf(a1 * c1v + a0 * s1);
      }
    } else {
      const int g = hh - 20;
      unsigned short* vbase = vout + (size_t)(b * NHK + g) * 128 * SEQ + l_base;
#pragma unroll 4
      for (int dd = 0; dd < 16; ++dd) {
        const int dcol = wave * 16 + dd;
        unsigned short* dst = vbase + (size_t)dcol * SEQ;
        dst[t64]      = epi[t64 * 129 + dcol];
        dst[t64 + 64] = epi[(t64 + 64) * 129 + dcol];
      }
    }
  }
}

// ---------------------------------------------------------------------------
// bf16 MFMA GEMM: C = A @ B, fp32 out (Wo). (unchanged from R7/R8)
// ---------------------------------------------------------------------------
__global__ __launch_bounds__(512, 2) void gemm_bf16_f32(const unsigned short* __restrict__ A,
                                                        const unsigned short* __restrict__ Bt,
                                                        float* __restrict__ C,
                                                        int M, int N, int K) {
  __shared__ unsigned short lds[49152];   // 96 KB: A 32KB | B 64KB
  unsigned short* ldsA = lds;
  unsigned short* ldsB = lds + 16384;

  const int tid = threadIdx.x;
  const int wave = tid >> 6;
  const int lane = tid & 63;
  const int m15 = lane & 15;
  const int quad = lane >> 4;
  const int wr = wave >> 2;
  const int wcol = wave & 3;
  const int bm = blockIdx.y * 128;
  const int bn = blockIdx.x * 256;

  floatx4 acc[4][4];
#pragma unroll
  for (int i = 0; i < 4; ++i)
#pragma unroll
    for (int j = 0; j < 4; ++j) acc[i][j] = (floatx4){0.f, 0.f, 0.f, 0.f};

  const int srow = tid >> 2;
  const int csrc = ((tid & 3) ^ ((tid >> 3) & 3)) * 8;
  const unsigned short* gA = A + (size_t)(bm + srow) * 2048 + csrc;
  const unsigned short* gB = Bt + (size_t)(bn + srow) * 2048 + csrc;
  const int wslot = wave * 512;

  const int rc = (quad ^ ((m15 >> 1) & 3)) * 8;
  const int aoff = (wr * 64 + m15) * 32 + rc;
  const int boff = (wcol * 64 + m15) * 32 + rc;

  stg1(gA + 0,  ldsA + wslot);
  stg2(gB + 0,  ldsB + wslot);
  stg1(gA + 32, ldsA + 4096 + wslot);
  stg2(gB + 32, ldsB + 8192 + wslot);
  stg1(gA + 64, ldsA + 8192 + wslot);
  stg2(gB + 64, ldsB + 16384 + wslot);
  asm volatile("s_waitcnt vmcnt(0)" ::: "memory");
  __builtin_amdgcn_s_barrier();
  __builtin_amdgcn_sched_barrier(0);

  const int NK = 32;
  short8 af[4], bv[4];
  for (int t = 0; t < NK; ++t) {
    const int d = t & 1;
    unsigned short* Ab = ldsA + d * 8192;
    unsigned short* Bb = ldsB + d * 16384;
    unsigned short* Aalt = ldsA + (d ^ 1) * 8192;
    unsigned short* Balt = ldsB + (d ^ 1) * 16384;
    const bool st1 = (t + 1 < NK), st2 = (t + 2 < NK);
    const int k1 = (t + 1) * 64 + 32;
    const int k2 = (t + 2) * 64;

    ld4(af, Ab + aoff);
    ld4(bv, Bb + boff);
    if (st1) { stg1(gA + k1, Aalt + 4096 + wslot);
               stg2(gB + k1, Balt + 8192 + wslot); }
    PBAR();
    __builtin_amdgcn_s_setprio(1);
    mfma_q(acc, af, bv);
    __builtin_amdgcn_s_setprio(0);
    KWAIT6(st2);
    PBAR();

    ld4(af, Ab + 4096 + aoff);
    ld4(bv, Bb + 8192 + boff);
    if (st2) { stg1(gA + k2, Ab + wslot);
               stg2(gB + k2, Bb + wslot); }
    PBAR();
    __builtin_amdgcn_s_setprio(1);
    mfma_q(acc, af, bv);
    __builtin_amdgcn_s_setprio(0);
    KWAIT6(st2);
    PBAR();
  }

#pragma unroll
  for (int i = 0; i < 4; ++i)
#pragma unroll
    for (int j = 0; j < 4; ++j)
#pragma unroll
      for (int r = 0; r < 4; ++r) {
        const int col = bn + wcol * 64 + j * 16 + m15;
        C[(size_t)(bm + wr * 64 + i * 16 + quad * 4 + r) * N + col] = acc[i][j][r];
      }
}

// ---------------------------------------------------------------------------
// MFMA flash attention (causal GQA), no-max softmax.
// R17: QBLK 64 -> 128 (32 Q-rows per wave, two 16-row fragments r16=0,1).
// Mechanism: each wave's 16 Ks b128 reads now feed 32 QK MFMAs (was 16),
// and 16 Vs reads feed 32 PV MFMAs -- 2x LDS arithmetic intensity; staging
// traffic per output row halves (same 32KB/tile, half the blocks).
// Ps = 128x72 hw (18KB) unioned over Ks (64x128, 16KB); Vs 16KB -> 34KB
// LDS, 2 blocks/CU. __launch_bounds__(256,2): VGPR cap 256 for the ~170
// live set (qf 32 + acc_s 32 + acc_o 64) -- R5/R8 lesson: never cap below
// the live set, spills cost 2.2x.
// Causal: mask gate j0 >= q0 covers both diagonal tiles; the fully-masked
// half-tile (waves 0-1 at j0=q0+64) computes zeros (~3% waste, correct).
// ---------------------------------------------------------------------------
__global__ __launch_bounds__(256, 2) void attn_mfma(const unsigned short* __restrict__ qb,
                                                    const unsigned short* __restrict__ kb,
                                                    const unsigned short* __restrict__ vtb,
                                                    unsigned short* __restrict__ o) {
  __shared__ unsigned short KsPs[128 * 72];   // 18KB union: K tile 64x128 / Ps 128x72
  __shared__ unsigned short Vs[128 * 64];     // 16KB
  unsigned short* Ks = KsPs;
  unsigned short* Ps = KsPs;

  const int tid = threadIdx.x;
  const int wave = tid >> 6;
  const int lane = tid & 63;
  const int m15 = lane & 15;
  const int quad = lane >> 4;
  const int bh = blockIdx.x;           // 0..31
  const int b = bh >> 4;
  const int h = bh & 15;
  const int g = h >> 2;
  const int q0 = ((int)gridDim.y - 1 - (int)blockIdx.y) * 128;  // longest first

  const unsigned short* qhead = qb + (size_t)bh * SEQ * 128;
  const unsigned short* khead = kb + (size_t)(b * NHK + g) * SEQ * 128;
  const unsigned short* vthead = vtb + (size_t)(b * NHK + g) * 128 * SEQ;

  short8 qf[2][4];
#pragma unroll
  for (int r16 = 0; r16 < 2; ++r16) {
    const unsigned short* qp =
        qhead + (size_t)(q0 + wave * 32 + r16 * 16 + m15) * 128 + quad * 8;
#pragma unroll
    for (int ks = 0; ks < 4; ++ks) qf[r16][ks] = *(const short8*)(qp + ks * 32);
  }

  floatx4 acc_o[2][8];
#pragma unroll
  for (int r16 = 0; r16 < 2; ++r16)
#pragma unroll
    for (int n = 0; n < 8; ++n) acc_o[r16][n] = (floatx4){0.f, 0.f, 0.f, 0.f};
  float l_lane[2][4] = {{0.f, 0.f, 0.f, 0.f}, {0.f, 0.f, 0.f, 0.f}};
  const float inv_scale = 1.0f / 16384.0f;

  for (int j0 = 0; j0 <= q0 + 64; j0 += 64) {
    // ---- stage K tile (64 x 128, chunk-XOR swizzle) and Vt tile (128 x 64)
#pragma unroll
    for (int t = 0; t < 4; ++t) {
      const int r = wave * 16 + t * 4 + (lane >> 4);
      const int cg = (lane & 15) ^ (r & 15);
      const unsigned short* src = khead + (size_t)(j0 + r) * 128 + cg * 8;
      __builtin_amdgcn_global_load_lds(
          (const AS1 void*)src,
          (AS3 void*)&Ks[(wave * 16 + t * 4) * 128], 16, 0, 0);
    }
#pragma unroll
    for (int t = 0; t < 4; ++t) {
      const int d = wave * 32 + t * 8 + (lane >> 3);
      const int cg = (lane & 7) ^ (d & 7);
      const unsigned short* src = vthead + (size_t)d * SEQ + j0 + cg * 8;
      __builtin_amdgcn_global_load_lds(
          (const AS1 void*)src,
          (AS3 void*)&Vs[(wave * 32 + t * 8) * 64], 16, 0, 0);
    }
    __syncthreads();

    // ---- S = Q K^T for both 16-row fragments; Ks bfrag loaded ONCE each.
    floatx4 acc_s[2][4];
#pragma unroll
    for (int r16 = 0; r16 < 2; ++r16)
#pragma unroll
      for (int n = 0; n < 4; ++n) acc_s[r16][n] = (floatx4){0.f, 0.f, 0.f, 0.f};
#pragma unroll
    for (int ks = 0; ks < 4; ++ks) {
#pragma unroll
      for (int n = 0; n < 4; ++n) {
        const short8 bfrag = *(const short8*)&Ks[(n * 16 + m15) * 128 + (((ks * 4 + quad) ^ m15) * 8)];
        acc_s[0][n] = __builtin_amdgcn_mfma_f32_16x16x32_bf16(qf[0][ks], bfrag, acc_s[0][n], 0, 0, 0);
        acc_s[1][n] = __builtin_amdgcn_mfma_f32_16x16x32_bf16(qf[1][ks], bfrag, acc_s[1][n], 0, 0, 0);
      }
    }
    __syncthreads();   // all waves done reading Ks before Ps overwrites it

    // ---- p = exp(s/16384) -> Ps; mask when j0 >= q0 (diagonal region).
    if (j0 >= q0) {
#pragma unroll
      for (int r16 = 0; r16 < 2; ++r16)
#pragma unroll
        for (int n = 0; n < 4; ++n) {
#pragma unroll
          for (int rg = 0; rg < 4; ++rg) {
            const int row_l = wave * 32 + r16 * 16 + quad * 4 + rg;
            const int col_l = n * 16 + m15;
            float p = (j0 + col_l > q0 + row_l) ? 0.0f
                                                : __expf(acc_s[r16][n][rg] * inv_scale);
            l_lane[r16][rg] += p;
            Ps[row_l * 72 + col_l] = f2bf(p);
          }
        }
    } else {
#pragma unroll
      for (int r16 = 0; r16 < 2; ++r16)
#pragma unroll
        for (int n = 0; n < 4; ++n) {
#pragma unroll
          for (int rg = 0; rg < 4; ++rg) {
            const float p = __expf(acc_s[r16][n][rg] * inv_scale);
            l_lane[r16][rg] += p;
            Ps[(wave * 32 + r16 * 16 + quad * 4 + rg) * 72 + n * 16 + m15] = f2bf(p);
          }
        }
    }

    // ---- O += P V; Vs bfrag loaded ONCE per (kk,n), used by both r16.
#pragma unroll
    for (int kk = 0; kk < 2; ++kk) {
      const short8 a0 = *(const short8*)&Ps[(wave * 32 + m15) * 72 + kk * 32 + quad * 8];
      const short8 a1 = *(const short8*)&Ps[(wave * 32 + 16 + m15) * 72 + kk * 32 + quad * 8];
#pragma unroll
      for (int n = 0; n < 8; ++n) {
        const short8 bfrag = *(const short8*)&Vs[(n * 16 + m15) * 64 + (((kk * 4 + quad) ^ (m15 & 7)) * 8)];
        acc_o[0][n] = __builtin_amdgcn_mfma_f32_16x16x32_bf16(a0, bfrag, acc_o[0][n], 0, 0, 0);
        acc_o[1][n] = __builtin_amdgcn_mfma_f32_16x16x32_bf16(a1, bfrag, acc_o[1][n], 0, 0, 0);
      }
    }
    __syncthreads();   // Ps reads done before next iteration restages Ks
  }

#pragma unroll
  for (int r16 = 0; r16 < 2; ++r16)
#pragma unroll
    for (int rg = 0; rg < 4; ++rg) {
      float l = l_lane[r16][rg];
      l += __shfl_xor(l, 1);
      l += __shfl_xor(l, 2);
      l += __shfl_xor(l, 4);
      l += __shfl_xor(l, 8);
      const float invl = 1.0f / l;
      const size_t row = (size_t)(b * SEQ + q0 + wave * 32 + r16 * 16 + quad * 4 + rg);
#pragma unroll
      for (int n = 0; n < 8; ++n)
        o[row * DMODEL + h * 128 + n * 16 + m15] = f2bf(acc_o[r16][n][rg] * invl);
    }
}

// ---------------------------------------------------------------------------
extern "C" void kernel_launch(void* const* d_in, const int* in_sizes, int n_in,
                              void* d_out, int out_size, void* d_ws, size_t ws_size,
                              hipStream_t stream) {
  const float* x       = (const float*)d_in[0];
  const float* Wq      = (const float*)d_in[1];
  const float* Wk      = (const float*)d_in[2];
  const float* Wv      = (const float*)d_in[3];
  const float* Wo      = (const float*)d_in[4];
  const float* q_scale = (const float*)d_in[5];
  const float* k_scale = (const float*)d_in[6];
  const float* cosb    = (const float*)d_in[7];
  const float* sinb    = (const float*)d_in[8];
  float* out = (float*)d_out;

  // Workspace (79.69 MB, no overlays; 83.9 MB proven available):
  char* w = (char*)d_ws;
  unsigned short* x_bf    = (unsigned short*)w;               // [0, 16.78M)
  unsigned short* wqkv_t  = (unsigned short*)(w + 16777216);  // [16.78M, 29.36M)
  unsigned short* q_bf    = (unsigned short*)(w + 29360128);  // [29.36M, 46.14M)
  unsigned short* k_bf    = (unsigned short*)(w + 46137344);  // [46.14M, 50.33M)
  unsigned short* vt      = (unsigned short*)(w + 50331648);  // [50.33M, 54.53M)
  unsigned short* wo_t    = (unsigned short*)(w + 54525952);  // [54.53M, 62.91M)
  unsigned short* attn_bf = (unsigned short*)(w + 62914560);  // [62.91M, 79.69M)

  prep<<<dim3(64, 32, 4), dim3(32, 8), 0, stream>>>(x, Wq, Wk, Wv, Wo, x_bf, wqkv_t, wo_t);

  // QKV projection: 128x384 (3 heads) 2-phase pipeline, grid 8x32 = 256 = 1/CU.
  gemm_qkv_fused<<<dim3(8, 32), 512, 0, stream>>>(x_bf, wqkv_t, q_bf, k_bf, vt,
                                                  q_scale, k_scale, cosb, sinb);

  // Attention: QBLK=128 per block (32 rows/wave), grid 32x16 = 512 blocks.
  attn_mfma<<<dim3(2 * NHQ, SEQ / 128), 256, 0, stream>>>(q_bf, k_bf, vt, attn_bf);

  // Output projection: 128x256 2-phase pipeline, grid 8x32 = 256 blocks (1/CU).
  gemm_bf16_f32<<<dim3(2048 / 256, 4096 / 128), 512, 0, stream>>>(
      attn_bf, wo_t, out, 4096, 2048, 2048);
}

// Round 10
// 299.543 us; speedup vs baseline: 1.0372x; 1.0372x over previous
//
#include <hip/hip_runtime.h>
#include <math.h>

// Problem constants (fixed by reference):
// B=2, L=2048, D=2048, H=16, G=4, HD=128, EPS=1e-6, scale = 1/HD^2 = 1/16384
#define SEQ 2048
#define DMODEL 2048
#define NHQ 16
#define NHK 4

typedef __attribute__((ext_vector_type(8))) short short8;
typedef __attribute__((ext_vector_type(8))) unsigned short ushort8;
typedef __attribute__((ext_vector_type(4))) float floatx4;

#define AS1 __attribute__((address_space(1)))
#define AS3 __attribute__((address_space(3)))

__device__ __forceinline__ unsigned short f2bf(float f) {
  unsigned int u = __builtin_bit_cast(unsigned int, f);
  u += 0x7fffu + ((u >> 16) & 1u);   // round-to-nearest-even
  return (unsigned short)(u >> 16);
}
__device__ __forceinline__ float bf2f(unsigned short s) {
  unsigned int u = ((unsigned int)s) << 16;
  return __builtin_bit_cast(float, u);
}

// ---------------------------------------------------------------------------
// One prep launch: cast x -> bf16 AND all 4 weight transposes. (unchanged)
// ---------------------------------------------------------------------------
__global__ __launch_bounds__(256) void prep(const float* __restrict__ x,
                                            const float* __restrict__ Wq,
                                            const float* __restrict__ Wk,
                                            const float* __restrict__ Wv,
                                            const float* __restrict__ Wo,
                                            unsigned short* __restrict__ x_bf,
                                            unsigned short* __restrict__ wqkv_t,
                                            unsigned short* __restrict__ wo_t) {
  const int z = blockIdx.z;
  const int tx = threadIdx.x, ty = threadIdx.y;
  const int tid = ty * 32 + tx;
  if (z == 3) {
    const size_t base = ((size_t)(blockIdx.y * 64 + blockIdx.x)) * 4096 + (size_t)tid * 16;
    const float4 v0 = *(const float4*)(x + base);
    const float4 v1 = *(const float4*)(x + base + 4);
    const float4 v2 = *(const float4*)(x + base + 8);
    const float4 v3 = *(const float4*)(x + base + 12);
    ushort8 w0, w1;
    w0[0] = f2bf(v0.x); w0[1] = f2bf(v0.y); w0[2] = f2bf(v0.z); w0[3] = f2bf(v0.w);
    w0[4] = f2bf(v1.x); w0[5] = f2bf(v1.y); w0[6] = f2bf(v1.z); w0[7] = f2bf(v1.w);
    w1[0] = f2bf(v2.x); w1[1] = f2bf(v2.y); w1[2] = f2bf(v2.z); w1[3] = f2bf(v2.w);
    w1[4] = f2bf(v3.x); w1[5] = f2bf(v3.y); w1[6] = f2bf(v3.z); w1[7] = f2bf(v3.w);
    *(ushort8*)(x_bf + base) = w0;
    *(ushort8*)(x_bf + base + 8) = w1;
    return;
  }
  int bx = blockIdx.x;
  const float* in;
  unsigned short* out;
  int C;
  const int R = 2048;
  if (z == 0)      { in = Wq; out = wqkv_t;                          C = 2048; }
  else if (z == 1) { in = Wo; out = wo_t;                            C = 2048; }
  else {
    if (bx < 16)      { in = Wk; out = wqkv_t + (size_t)2048 * 2048; C = 512; }
    else if (bx < 32) { in = Wv; out = wqkv_t + (size_t)2560 * 2048; C = 512; bx -= 16; }
    else return;
  }
  __shared__ float tile[32][65];
  const int c0 = bx * 32, r0 = blockIdx.y * 64;
#pragma unroll
  for (int j = 0; j < 8; ++j)
    tile[tx][ty + j * 8] = in[(size_t)(r0 + ty + j * 8) * C + c0 + tx];
  __syncthreads();
  const int c = tid >> 3;
  const int l8 = tid & 7;
  ushort8 w;
#pragma unroll
  for (int u = 0; u < 8; ++u) w[u] = f2bf(tile[c][l8 * 8 + u]);
  *(ushort8*)(out + (size_t)(c0 + c) * R + r0 + l8 * 8) = w;
}

// ---------------------------------------------------------------------------
// Shared pipeline pieces (R15-verified swizzle + counted vmcnt).
// ---------------------------------------------------------------------------
#define PBAR() do { __builtin_amdgcn_sched_barrier(0); __builtin_amdgcn_s_barrier(); \
                    __builtin_amdgcn_sched_barrier(0); } while (0)
#define KWAIT8(deep) do { if (deep) asm volatile("s_waitcnt vmcnt(8)" ::: "memory"); \
                          else      asm volatile("s_waitcnt vmcnt(0)" ::: "memory"); } while (0)
#define KWAIT6(deep) do { if (deep) asm volatile("s_waitcnt vmcnt(6)" ::: "memory"); \
                          else      asm volatile("s_waitcnt vmcnt(0)" ::: "memory"); } while (0)

__device__ __forceinline__ void mfma_q(floatx4 (&ac)[4][4],
                                       const short8 (&a)[4], const short8 (&b)[4]) {
#pragma unroll
  for (int i = 0; i < 4; ++i)
#pragma unroll
    for (int j = 0; j < 4; ++j)
      ac[i][j] = __builtin_amdgcn_mfma_f32_16x16x32_bf16(a[i], b[j], ac[i][j], 0, 0, 0);
}

__device__ __forceinline__ void ld4(short8 (&v)[4], const unsigned short* p) {
#pragma unroll
  for (int i = 0; i < 4; ++i) v[i] = *(const short8*)(p + i * 512);
}
__device__ __forceinline__ void ld6(short8 (&v)[6], const unsigned short* p) {
#pragma unroll
  for (int i = 0; i < 6; ++i) v[i] = *(const short8*)(p + i * 512);
}

__device__ __forceinline__ void stg1(const unsigned short* src0,
                                     unsigned short* dst_uniform) {
  __builtin_amdgcn_global_load_lds((const AS1 void*)src0,
                                   (AS3 void*)dst_uniform, 16, 0, 0);
}
__device__ __forceinline__ void stg2(const unsigned short* src0,
                                     unsigned short* dst_uniform) {
  __builtin_amdgcn_global_load_lds((const AS1 void*)src0,
                                   (AS3 void*)dst_uniform, 16, 0, 0);
  __builtin_amdgcn_global_load_lds((const AS1 void*)(src0 + (size_t)128 * 2048),
                                   (AS3 void*)(dst_uniform + 4096), 16, 0, 0);
}
__device__ __forceinline__ void stg3(const unsigned short* src0,
                                     unsigned short* dst_uniform) {
  __builtin_amdgcn_global_load_lds((const AS1 void*)src0,
                                   (AS3 void*)dst_uniform, 16, 0, 0);
  __builtin_amdgcn_global_load_lds((const AS1 void*)(src0 + (size_t)128 * 2048),
                                   (AS3 void*)(dst_uniform + 4096), 16, 0, 0);
  __builtin_amdgcn_global_load_lds((const AS1 void*)(src0 + (size_t)256 * 2048),
                                   (AS3 void*)(dst_uniform + 8192), 16, 0, 0);
}

// ---------------------------------------------------------------------------
// Fused QKV GEMM + RMSNorm + RoPE + V-transpose, 128x384. (unchanged from R8)
// ---------------------------------------------------------------------------
__global__ __launch_bounds__(512, 2) void gemm_qkv_fused(const unsigned short* __restrict__ A,
                                                         const unsigned short* __restrict__ Bt,
                                                         unsigned short* __restrict__ qout,
                                                         unsigned short* __restrict__ kout,
                                                         unsigned short* __restrict__ vout,
                                                         const float* __restrict__ q_scale,
                                                         const float* __restrict__ k_scale,
                                                         const float* __restrict__ cosb,
                                                         const float* __restrict__ sinb) {
  __shared__ unsigned short lds[65536];   // 128 KB
  unsigned short* ldsA = lds;             // [buf*8192][kh*4096][128x32]
  unsigned short* ldsB = lds + 16384;     // [buf*24576][kh*12288][384x32]

  const int tid = threadIdx.x;
  const int wave = tid >> 6;
  const int lane = tid & 63;
  const int m15 = lane & 15;
  const int quad = lane >> 4;
  const int wr = wave >> 2;
  const int wcol = wave & 3;
  const int bxn = blockIdx.x;
  const int bm = blockIdx.y * 128;
  const int bn = bxn * 384;

  floatx4 acc[4][6];
#pragma unroll
  for (int i = 0; i < 4; ++i)
#pragma unroll
    for (int j = 0; j < 6; ++j) acc[i][j] = (floatx4){0.f, 0.f, 0.f, 0.f};

  const int srow = tid >> 2;
  const int csrc = ((tid & 3) ^ ((tid >> 3) & 3)) * 8;
  const unsigned short* gA = A + (size_t)(bm + srow) * 2048 + csrc;
  const unsigned short* gB = Bt + (size_t)(bn + srow) * 2048 + csrc;
  const int wslot = wave * 512;

  const int rc = (quad ^ ((m15 >> 1) & 3)) * 8;
  const int aoff = (wr * 64 + m15) * 32 + rc;
  const int boff = (wcol * 96 + m15) * 32 + rc;

  stg1(gA + 0,  ldsA + wslot);
  stg3(gB + 0,  ldsB + wslot);
  stg1(gA + 32, ldsA + 4096 + wslot);
  stg3(gB + 32, ldsB + 12288 + wslot);
  stg1(gA + 64, ldsA + 8192 + wslot);
  stg3(gB + 64, ldsB + 24576 + wslot);
  asm volatile("s_waitcnt vmcnt(0)" ::: "memory");
  __builtin_amdgcn_s_barrier();
  __builtin_amdgcn_sched_barrier(0);

  const int NK = 32;
  short8 af[4], bv[6];
  for (int t = 0; t < NK; ++t) {
    const int d = t & 1;
    unsigned short* Ab = ldsA + d * 8192;
    unsigned short* Bb = ldsB + d * 24576;
    unsigned short* Aalt = ldsA + (d ^ 1) * 8192;
    unsigned short* Balt = ldsB + (d ^ 1) * 24576;
    const bool st1 = (t + 1 < NK), st2 = (t + 2 < NK);
    const int k1 = (t + 1) * 64 + 32;
    const int k2 = (t + 2) * 64;

    ld4(af, Ab + aoff);
    ld6(bv, Bb + boff);
    if (st1) { stg1(gA + k1, Aalt + 4096 + wslot);
               stg3(gB + k1, Balt + 12288 + wslot); }
    PBAR();
    __builtin_amdgcn_s_setprio(1);
#pragma unroll
    for (int i = 0; i < 4; ++i)
#pragma unroll
      for (int j = 0; j < 6; ++j)
        acc[i][j] = __builtin_amdgcn_mfma_f32_16x16x32_bf16(af[i], bv[j], acc[i][j], 0, 0, 0);
    __builtin_amdgcn_s_setprio(0);
    KWAIT8(st2);
    PBAR();

    ld4(af, Ab + 4096 + aoff);
    ld6(bv, Bb + 12288 + boff);
    if (st2) { stg1(gA + k2, Ab + wslot);
               stg3(gB + k2, Bb + wslot); }
    PBAR();
    __builtin_amdgcn_s_setprio(1);
#pragma unroll
    for (int i = 0; i < 4; ++i)
#pragma unroll
      for (int j = 0; j < 6; ++j)
        acc[i][j] = __builtin_amdgcn_mfma_f32_16x16x32_bf16(af[i], bv[j], acc[i][j], 0, 0, 0);
    __builtin_amdgcn_s_setprio(0);
    KWAIT8(st2);
    PBAR();
  }

  // ---- epilogue: three per-head passes through a 128x129 LDS region.
  unsigned short* epi = lds;
  const int b = bm >> 11;
  const int l_base = bm & (SEQ - 1);
  const int t64 = tid & 63;

  for (int c = 0; c < 3; ++c) {
    __syncthreads();
#pragma unroll
    for (int j = 0; j < 6; ++j) {
      const int head16 = 6 * wcol + j;
      if ((head16 >> 3) == c) {
        const int incol = (head16 & 7) * 16 + m15;
#pragma unroll
        for (int i = 0; i < 4; ++i)
#pragma unroll
          for (int r = 0; r < 4; ++r)
            epi[(wr * 64 + i * 16 + quad * 4 + r) * 129 + incol] = f2bf(acc[i][j][r]);
      }
    }
    __syncthreads();

    const int hh = 3 * bxn + c;
    if (hh < 20) {
      const float* scale = (hh < NHQ) ? q_scale : k_scale;
      unsigned short* dstbase = (hh < NHQ)
          ? qout + ((size_t)(b * NHQ + hh) * SEQ + l_base) * 128
          : kout + ((size_t)(b * NHK + (hh - NHQ)) * SEQ + l_base) * 128;
      const float sc0 = scale[t64];
      const float sc1 = scale[t64 + 64];
#pragma unroll 4
      for (int rr = 0; rr < 16; ++rr) {
        const int row = wave * 16 + rr;
        const float v0 = bf2f(epi[row * 129 + t64]);
        const float v1 = bf2f(epi[row * 129 + t64 + 64]);
        float ss = v0 * v0 + v1 * v1;
#pragma unroll
        for (int m = 1; m < 64; m <<= 1) ss += __shfl_xor(ss, m);
        const float r = rsqrtf(ss * (1.0f / 128.0f) + 1e-6f);
        const int l = l_base + row;
        const float c0v = cosb[(size_t)l * 128 + t64];
        const float s0 = sinb[(size_t)l * 128 + t64];
        const float c1v = cosb[(size_t)l * 128 + t64 + 64];
        const float s1 = sinb[(size_t)l * 128 + t64 + 64];
        const float a0 = v0 * r * sc0;
        const float a1 = v1 * r * sc1;
        unsigned short* dst = dstbase + (size_t)row * 128;
        dst[t64]      = f2bf(a0 * c0v - a1 * s0);
        dst[t64 + 64] = f2bf(a1 * c1v + a0 * s1);
      }
    } else {
      const int g = hh - 20;
      unsigned short* vbase = vout + (size_t)(b * NHK + g) * 128 * SEQ + l_base;
#pragma unroll 4
      for (int dd = 0; dd < 16; ++dd) {
        const int dcol = wave * 16 + dd;
        unsigned short* dst = vbase + (size_t)dcol * SEQ;
        dst[t64]      = epi[t64 * 129 + dcol];
        dst[t64 + 64] = epi[(t64 + 64) * 129 + dcol];
      }
    }
  }
}

// ---------------------------------------------------------------------------
// bf16 MFMA GEMM: C = A @ B, fp32 out (Wo). (unchanged from R7/R8)
// ---------------------------------------------------------------------------
__global__ __launch_bounds__(512, 2) void gemm_bf16_f32(const unsigned short* __restrict__ A,
                                                        const unsigned short* __restrict__ Bt,
                                                        float* __restrict__ C,
                                                        int M, int N, int K) {
  __shared__ unsigned short lds[49152];   // 96 KB: A 32KB | B 64KB
  unsigned short* ldsA = lds;
  unsigned short* ldsB = lds + 16384;

  const int tid = threadIdx.x;
  const int wave = tid >> 6;
  const int lane = tid & 63;
  const int m15 = lane & 15;
  const int quad = lane >> 4;
  const int wr = wave >> 2;
  const int wcol = wave & 3;
  const int bm = blockIdx.y * 128;
  const int bn = blockIdx.x * 256;

  floatx4 acc[4][4];
#pragma unroll
  for (int i = 0; i < 4; ++i)
#pragma unroll
    for (int j = 0; j < 4; ++j) acc[i][j] = (floatx4){0.f, 0.f, 0.f, 0.f};

  const int srow = tid >> 2;
  const int csrc = ((tid & 3) ^ ((tid >> 3) & 3)) * 8;
  const unsigned short* gA = A + (size_t)(bm + srow) * 2048 + csrc;
  const unsigned short* gB = Bt + (size_t)(bn + srow) * 2048 + csrc;
  const int wslot = wave * 512;

  const int rc = (quad ^ ((m15 >> 1) & 3)) * 8;
  const int aoff = (wr * 64 + m15) * 32 + rc;
  const int boff = (wcol * 64 + m15) * 32 + rc;

  stg1(gA + 0,  ldsA + wslot);
  stg2(gB + 0,  ldsB + wslot);
  stg1(gA + 32, ldsA + 4096 + wslot);
  stg2(gB + 32, ldsB + 8192 + wslot);
  stg1(gA + 64, ldsA + 8192 + wslot);
  stg2(gB + 64, ldsB + 16384 + wslot);
  asm volatile("s_waitcnt vmcnt(0)" ::: "memory");
  __builtin_amdgcn_s_barrier();
  __builtin_amdgcn_sched_barrier(0);

  const int NK = 32;
  short8 af[4], bv[4];
  for (int t = 0; t < NK; ++t) {
    const int d = t & 1;
    unsigned short* Ab = ldsA + d * 8192;
    unsigned short* Bb = ldsB + d * 16384;
    unsigned short* Aalt = ldsA + (d ^ 1) * 8192;
    unsigned short* Balt = ldsB + (d ^ 1) * 16384;
    const bool st1 = (t + 1 < NK), st2 = (t + 2 < NK);
    const int k1 = (t + 1) * 64 + 32;
    const int k2 = (t + 2) * 64;

    ld4(af, Ab + aoff);
    ld4(bv, Bb + boff);
    if (st1) { stg1(gA + k1, Aalt + 4096 + wslot);
               stg2(gB + k1, Balt + 8192 + wslot); }
    PBAR();
    __builtin_amdgcn_s_setprio(1);
    mfma_q(acc, af, bv);
    __builtin_amdgcn_s_setprio(0);
    KWAIT6(st2);
    PBAR();

    ld4(af, Ab + 4096 + aoff);
    ld4(bv, Bb + 8192 + boff);
    if (st2) { stg1(gA + k2, Ab + wslot);
               stg2(gB + k2, Bb + wslot); }
    PBAR();
    __builtin_amdgcn_s_setprio(1);
    mfma_q(acc, af, bv);
    __builtin_amdgcn_s_setprio(0);
    KWAIT6(st2);
    PBAR();
  }

#pragma unroll
  for (int i = 0; i < 4; ++i)
#pragma unroll
    for (int j = 0; j < 4; ++j)
#pragma unroll
      for (int r = 0; r < 4; ++r) {
        const int col = bn + wcol * 64 + j * 16 + m15;
        C[(size_t)(bm + wr * 64 + i * 16 + quad * 4 + r) * N + col] = acc[i][j][r];
      }
}

// ---------------------------------------------------------------------------
// MFMA flash attention (causal GQA), no-max softmax.
// R18: 8 waves x 16 Q-rows (QBLK=128), grid (32,16) = 512 blocks = 2/CU.
// R17 lesson (measured): OccupancyPercent 12.8% = ~4 waves/CU average --
// with 2 static blocks/CU and 2..32-tile work variance, the short block
// finishes and the long block runs ALONE (4 waves, no TLP). Fixes:
//  (a) 8 waves/block -> 16 waves/CU resident (launch_bounds(512,4),
//      VGPR cap 128 >= ~90 live set; LDS 34KB -> 2 blocks/CU).
//  (b) uniform work pairing: co-resident blocks are c and c+256 (by
//      differs by 8); remap fy = yy<8 ? 15-yy : yy-8 (bijection) so each
//      CU's pair sums to exactly 34 tiles -- no decay tail.
// Keeps R17's 2x K/V amortization: one 64-KV tile serves 128 Q rows.
// Causal: mask gate j0 >= q0 covers both diagonal tiles; waves 0..3 on
// the last tile compute zeros (~3% waste, correct).
// ---------------------------------------------------------------------------
__global__ __launch_bounds__(512, 4) void attn_mfma(const unsigned short* __restrict__ qb,
                                                    const unsigned short* __restrict__ kb,
                                                    const unsigned short* __restrict__ vtb,
                                                    unsigned short* __restrict__ o) {
  __shared__ unsigned short KsPs[128 * 72];   // 18KB union: K tile 64x128 / Ps 128x72
  __shared__ unsigned short Vs[128 * 64];     // 16KB
  unsigned short* Ks = KsPs;
  unsigned short* Ps = KsPs;

  const int tid = threadIdx.x;
  const int wave = tid >> 6;           // 0..7
  const int lane = tid & 63;
  const int m15 = lane & 15;
  const int quad = lane >> 4;
  const int bh = blockIdx.x;           // 0..31
  const int b = bh >> 4;
  const int h = bh & 15;
  const int g = h >> 2;
  const int yy = blockIdx.y;           // 0..15
  const int fy = (yy < 8) ? (15 - yy) : (yy - 8);   // pair-complement remap
  const int q0 = fy * 128;

  const unsigned short* qhead = qb + (size_t)bh * SEQ * 128;
  const unsigned short* khead = kb + (size_t)(b * NHK + g) * SEQ * 128;
  const unsigned short* vthead = vtb + (size_t)(b * NHK + g) * 128 * SEQ;

  short8 qf[4];
  {
    const unsigned short* qp = qhead + (size_t)(q0 + wave * 16 + m15) * 128 + quad * 8;
#pragma unroll
    for (int ks = 0; ks < 4; ++ks) qf[ks] = *(const short8*)(qp + ks * 32);
  }

  floatx4 acc_o[8];
#pragma unroll
  for (int n = 0; n < 8; ++n) acc_o[n] = (floatx4){0.f, 0.f, 0.f, 0.f};
  float l_lane[4] = {0.f, 0.f, 0.f, 0.f};
  const float inv_scale = 1.0f / 16384.0f;

  for (int j0 = 0; j0 <= q0 + 64; j0 += 64) {
    // ---- stage K tile (64x128, chunk-XOR swizzle): 512 thr x 2 loads.
#pragma unroll
    for (int t = 0; t < 2; ++t) {
      const int r = wave * 8 + t * 4 + (lane >> 4);
      const int cg = (lane & 15) ^ (r & 15);
      const unsigned short* src = khead + (size_t)(j0 + r) * 128 + cg * 8;
      __builtin_amdgcn_global_load_lds(
          (const AS1 void*)src,
          (AS3 void*)&Ks[(wave * 8 + t * 4) * 128], 16, 0, 0);
    }
    // ---- stage Vt tile (128x64): 512 thr x 2 loads.
#pragma unroll
    for (int t = 0; t < 2; ++t) {
      const int d = wave * 16 + t * 8 + (lane >> 3);
      const int cg = (lane & 7) ^ (d & 7);
      const unsigned short* src = vthead + (size_t)d * SEQ + j0 + cg * 8;
      __builtin_amdgcn_global_load_lds(
          (const AS1 void*)src,
          (AS3 void*)&Vs[(wave * 16 + t * 8) * 64], 16, 0, 0);
    }
    __syncthreads();

    // ---- S = Q K^T (each wave: 16 own Q rows x full 64-col K tile).
    floatx4 acc_s[4];
#pragma unroll
    for (int n = 0; n < 4; ++n) acc_s[n] = (floatx4){0.f, 0.f, 0.f, 0.f};
#pragma unroll
    for (int ks = 0; ks < 4; ++ks) {
#pragma unroll
      for (int n = 0; n < 4; ++n) {
        const short8 bfrag = *(const short8*)&Ks[(n * 16 + m15) * 128 + (((ks * 4 + quad) ^ m15) * 8)];
        acc_s[n] = __builtin_amdgcn_mfma_f32_16x16x32_bf16(qf[ks], bfrag, acc_s[n], 0, 0, 0);
      }
    }
    __syncthreads();   // all waves done reading Ks before Ps overwrites it

    // ---- p = exp(s/16384) -> Ps; mask when j0 >= q0 (diagonal region).
    if (j0 >= q0) {
#pragma unroll
      for (int n = 0; n < 4; ++n) {
#pragma unroll
        for (int rg = 0; rg < 4; ++rg) {
          const int row_l = wave * 16 + quad * 4 + rg;
          const int col_l = n * 16 + m15;
          float p = (j0 + col_l > q0 + row_l) ? 0.0f
                                              : __expf(acc_s[n][rg] * inv_scale);
          l_lane[rg] += p;
          Ps[row_l * 72 + col_l] = f2bf(p);
        }
      }
    } else {
#pragma unroll
      for (int n = 0; n < 4; ++n) {
#pragma unroll
        for (int rg = 0; rg < 4; ++rg) {
          const float p = __expf(acc_s[n][rg] * inv_scale);
          l_lane[rg] += p;
          Ps[(wave * 16 + quad * 4 + rg) * 72 + n * 16 + m15] = f2bf(p);
        }
      }
    }

    // ---- O += P V  (Ps rows wave-private: same-wave write->read, in-order)
#pragma unroll
    for (int kk = 0; kk < 2; ++kk) {
      const short8 a = *(const short8*)&Ps[(wave * 16 + m15) * 72 + kk * 32 + quad * 8];
#pragma unroll
      for (int n = 0; n < 8; ++n) {
        const short8 bfrag = *(const short8*)&Vs[(n * 16 + m15) * 64 + (((kk * 4 + quad) ^ (m15 & 7)) * 8)];
        acc_o[n] = __builtin_amdgcn_mfma_f32_16x16x32_bf16(a, bfrag, acc_o[n], 0, 0, 0);
      }
    }
    __syncthreads();   // Ps reads done before next iteration restages Ks
  }

#pragma unroll
  for (int rg = 0; rg < 4; ++rg) {
    float l = l_lane[rg];
    l += __shfl_xor(l, 1);
    l += __shfl_xor(l, 2);
    l += __shfl_xor(l, 4);
    l += __shfl_xor(l, 8);
    const float invl = 1.0f / l;
    const size_t row = (size_t)(b * SEQ + q0 + wave * 16 + quad * 4 + rg);
#pragma unroll
    for (int n = 0; n < 8; ++n)
      o[row * DMODEL + h * 128 + n * 16 + m15] = f2bf(acc_o[n][rg] * invl);
  }
}

// ---------------------------------------------------------------------------
extern "C" void kernel_launch(void* const* d_in, const int* in_sizes, int n_in,
                              void* d_out, int out_size, void* d_ws, size_t ws_size,
                              hipStream_t stream) {
  const float* x       = (const float*)d_in[0];
  const float* Wq      = (const float*)d_in[1];
  const float* Wk      = (const float*)d_in[2];
  const float* Wv      = (const float*)d_in[3];
  const float* Wo      = (const float*)d_in[4];
  const float* q_scale = (const float*)d_in[5];
  const float* k_scale = (const float*)d_in[6];
  const float* cosb    = (const float*)d_in[7];
  const float* sinb    = (const float*)d_in[8];
  float* out = (float*)d_out;

  // Workspace (79.69 MB, no overlays; 83.9 MB proven available):
  char* w = (char*)d_ws;
  unsigned short* x_bf    = (unsigned short*)w;               // [0, 16.78M)
  unsigned short* wqkv_t  = (unsigned short*)(w + 16777216);  // [16.78M, 29.36M)
  unsigned short* q_bf    = (unsigned short*)(w + 29360128);  // [29.36M, 46.14M)
  unsigned short* k_bf    = (unsigned short*)(w + 46137344);  // [46.14M, 50.33M)
  unsigned short* vt      = (unsigned short*)(w + 50331648);  // [50.33M, 54.53M)
  unsigned short* wo_t    = (unsigned short*)(w + 54525952);  // [54.53M, 62.91M)
  unsigned short* attn_bf = (unsigned short*)(w + 62914560);  // [62.91M, 79.69M)

  prep<<<dim3(64, 32, 4), dim3(32, 8), 0, stream>>>(x, Wq, Wk, Wv, Wo, x_bf, wqkv_t, wo_t);

  // QKV projection: 128x384 (3 heads) 2-phase pipeline, grid 8x32 = 256 = 1/CU.
  gemm_qkv_fused<<<dim3(8, 32), 512, 0, stream>>>(x_bf, wqkv_t, q_bf, k_bf, vt,
                                                  q_scale, k_scale, cosb, sinb);

  // Attention: QBLK=128, 8 waves x 16 rows, grid 32x16 = 512 blocks = 2/CU,
  // pair-complement y-remap for uniform per-CU work.
  attn_mfma<<<dim3(2 * NHQ, SEQ / 128), 512, 0, stream>>>(q_bf, k_bf, vt, attn_bf);

  // Output projection: 128x256 2-phase pipeline, grid 8x32 = 256 blocks (1/CU).
  gemm_bf16_f32<<<dim3(2048 / 256, 4096 / 128), 512, 0, stream>>>(
      attn_bf, wo_t, out, 4096, 2048, 2048);
}